// Round 1
// baseline (198.651 us; speedup 1.0000x reference)
//
#include <hip/hip_runtime.h>

typedef float f32x2 __attribute__((ext_vector_type(2)));
typedef float f32x4 __attribute__((ext_vector_type(4)));

// DPP quad_perm helpers: exchange within quads, pure VALU (no LDS, no barriers).
__device__ __forceinline__ float dpp_xor1(float v) {
  // quad_perm:[1,0,3,2] = 0xB1
  int r = __builtin_amdgcn_update_dpp(0, __builtin_bit_cast(int, v), 0xB1, 0xF, 0xF, true);
  return __builtin_bit_cast(float, r);
}
__device__ __forceinline__ float dpp_xor2(float v) {
  // quad_perm:[2,3,0,1] = 0x4E
  int r = __builtin_amdgcn_update_dpp(0, __builtin_bit_cast(int, v), 0x4E, 0xF, 0xF, true);
  return __builtin_bit_cast(float, r);
}

__global__ __launch_bounds__(256, 4) void mnist_fused(
    const float* __restrict__ x,
    const float* __restrict__ W1, const float* __restrict__ b1,
    const float* __restrict__ W2, const float* __restrict__ b2,
    const float* __restrict__ W3, const float* __restrict__ b3,
    float* __restrict__ out, int nimg)
{
  // Weights staged to LDS, transposed so the inner streams are contiguous.
  __shared__ __align__(16) float sW1t[49 * 16];   // [p][f]
  __shared__ __align__(16) float sW2t[64 * 16];   // [k][f2]
  __shared__ __align__(16) float sW3[10 * 64];    // [o][m]
  __shared__ float sB1[16], sB2[16], sB3[10];

  const int tid = threadIdx.x;
  for (int idx = tid; idx < 49 * 16; idx += 256) {
    int f = idx / 49, p = idx - f * 49;
    sW1t[p * 16 + f] = W1[idx];
  }
  for (int idx = tid; idx < 64 * 16; idx += 256) {
    int f2 = idx >> 6, k = idx & 63;
    sW2t[k * 16 + f2] = W2[idx];
  }
  for (int idx = tid; idx < 10 * 64; idx += 256) sW3[idx] = W3[idx];
  if (tid < 16) sB1[tid] = b1[tid];
  else if (tid < 32) sB2[tid - 16] = b2[tid - 16];
  else if (tid < 42) sB3[tid - 32] = b3[tid - 32];
  __syncthreads();

  // 4 lanes per image: lane handles one 7-row band (contiguous 196 floats).
  int g = (int)(blockIdx.x * 256u + tid) >> 2;
  if (g >= nimg) g = nimg - 1;           // duplicate work, identical output: safe
  const int band = tid & 3;              // band i = rows 7i..7i+6 ; also L2 position index
  const bool Jb = (band & 1) != 0;       // L2 position (I,J) = (band>>1, band&1)

  const f32x4* __restrict__ xq = (const f32x4*)x + (size_t)g * 196 + (size_t)band * 49;

  // ---------------- Layer 1: h[j][f] for j=0..3 (this band's 4 patches) ----
  f32x2 acc[4][8];
#pragma unroll
  for (int fp = 0; fp < 8; ++fp) {
    f32x2 bb = { sB1[2 * fp], sB1[2 * fp + 1] };
    acc[0][fp] = bb; acc[1][fp] = bb; acc[2][fp] = bb; acc[3][fp] = bb;
  }

#pragma unroll
  for (int lr = 0; lr < 7; ++lr) {       // local row within band
    f32x4 r[7];
#pragma unroll
    for (int q = 0; q < 7; ++q) r[q] = xq[lr * 7 + q];   // 28 floats = one image row
#pragma unroll
    for (int cc = 0; cc < 7; ++cc) {     // local col within patch
      const int p = lr * 7 + cc;         // intra-patch index, wave-uniform
      const f32x4* wp = (const f32x4*)(sW1t + p * 16);
      f32x4 w0 = wp[0], w1 = wp[1], w2 = wp[2], w3 = wp[3];   // broadcast ds_read_b128
      f32x2 wv[8] = { {w0.x,w0.y},{w0.z,w0.w},{w1.x,w1.y},{w1.z,w1.w},
                      {w2.x,w2.y},{w2.z,w2.w},{w3.x,w3.y},{w3.z,w3.w} };
#pragma unroll
      for (int j = 0; j < 4; ++j) {      // patch column j, element col = 7j+cc
        const int e = j * 7 + cc;        // 0..27, compile-time
        float v = r[e >> 2][e & 3];
        f32x2 vv = { v, v };
#pragma unroll
        for (int fp = 0; fp < 8; ++fp)
          acc[j][fp] = __builtin_elementwise_fma(wv[fp], vv, acc[j][fp]);
      }
    }
  }

  // ---------------- Layer 2: y[f2] for this lane's position (I,J) ----------
  // hb[(i2*2+j2)*16+f] = h[2I+i2][2J+j2][f]. Source band 2I+i2 is own lane
  // (i2==J) or lane^1 (i2!=J). Cross-lane via DPP quad_perm xor1.
  f32x2 acc2[8];
#pragma unroll
  for (int fp = 0; fp < 8; ++fp) acc2[fp] = f32x2{ sB2[2 * fp], sB2[2 * fp + 1] };

#pragma unroll
  for (int j2 = 0; j2 < 2; ++j2) {
#pragma unroll
    for (int f = 0; f < 16; ++f) {
      float c0 = acc[j2][f >> 1][f & 1];        // own h[j2][f]      (a = 2J+j2 if J==0)
      float c1 = acc[2 + j2][f >> 1][f & 1];    // own h[2+j2][f]    (a = 2J+j2 if J==1)
      float own  = Jb ? c1 : c0;                // h[band][2J+j2][f]       (i2 == J)
      float flip = Jb ? c0 : c1;                // value the NEIGHBOR needs from us
      float nb = dpp_xor1(flip);                // neighbor's h[band^1][2J+j2][f]
      float hb0 = Jb ? nb : own;                // i2 = 0
      float hb1 = Jb ? own : nb;                // i2 = 1
      const f32x4* wq0 = (const f32x4*)(sW2t + (j2 * 16 + f) * 16);        // k0
      const f32x4* wq1 = (const f32x4*)(sW2t + ((2 + j2) * 16 + f) * 16);  // k1
      f32x2 v0 = { hb0, hb0 }, v1 = { hb1, hb1 };
#pragma unroll
      for (int t = 0; t < 4; ++t) {
        f32x4 a = wq0[t], b = wq1[t];
        acc2[2 * t]     = __builtin_elementwise_fma(f32x2{a.x, a.y}, v0, acc2[2 * t]);
        acc2[2 * t + 1] = __builtin_elementwise_fma(f32x2{a.z, a.w}, v0, acc2[2 * t + 1]);
        acc2[2 * t]     = __builtin_elementwise_fma(f32x2{b.x, b.y}, v1, acc2[2 * t]);
        acc2[2 * t + 1] = __builtin_elementwise_fma(f32x2{b.z, b.w}, v1, acc2[2 * t + 1]);
      }
    }
  }

  // ---------------- ReLU + Layer 3 + quad reduction ------------------------
  float yr[16];
#pragma unroll
  for (int fp = 0; fp < 8; ++fp) {
    yr[2 * fp]     = fmaxf(acc2[fp].x, 0.f);
    yr[2 * fp + 1] = fmaxf(acc2[fp].y, 0.f);
  }

  float z[10];
#pragma unroll
  for (int o = 0; o < 10; ++o) {
    const f32x4* wr = (const f32x4*)(sW3 + o * 64 + band * 16);
    float s = 0.f;
#pragma unroll
    for (int t = 0; t < 4; ++t) {
      f32x4 w = wr[t];
      s = fmaf(w.x, yr[4 * t + 0], s);
      s = fmaf(w.y, yr[4 * t + 1], s);
      s = fmaf(w.z, yr[4 * t + 2], s);
      s = fmaf(w.w, yr[4 * t + 3], s);
    }
    s += dpp_xor1(s);          // butterfly sum over the 4 lanes of this image
    s += dpp_xor2(s);
    z[o] = s + sB3[o];
  }

  // ---------------- log_softmax + store ------------------------------------
  float m = z[0];
#pragma unroll
  for (int o = 1; o < 10; ++o) m = fmaxf(m, z[o]);
  float ssum = 0.f;
#pragma unroll
  for (int o = 0; o < 10; ++o) ssum += __expf(z[o] - m);
  const float lse = m + __logf(ssum);

  float* op = out + (size_t)g * 10;
  for (int o = band; o < 10; o += 4) op[o] = z[o] - lse;
}

extern "C" void kernel_launch(void* const* d_in, const int* in_sizes, int n_in,
                              void* d_out, int out_size, void* d_ws, size_t ws_size,
                              hipStream_t stream) {
  const float* x  = (const float*)d_in[0];
  const float* W1 = (const float*)d_in[1];
  const float* b1 = (const float*)d_in[2];
  const float* W2 = (const float*)d_in[3];
  const float* b2 = (const float*)d_in[4];
  const float* W3 = (const float*)d_in[5];
  const float* b3 = (const float*)d_in[6];
  float* out = (float*)d_out;

  const int nimg = in_sizes[0] / 784;          // 131072
  const int blocks = (nimg * 4 + 255) / 256;   // 4 lanes per image
  mnist_fused<<<blocks, 256, 0, stream>>>(x, W1, b1, W2, b2, W3, b3, out, nimg);
}